// Round 9
// baseline (4681.892 us; speedup 1.0000x reference)
//
#include <hip/hip_runtime.h>
#include <stdint.h>
#include <stddef.h>

// Problem dims
#define Mdim 2048
#define Tdim 64
#define INdim 16
#define Hdim 256
#define NCdim 64

// Partition: 8 rg (256 rows) x 64 ug (4 units). Step waves: (unit-pair, row-half).
#define S0P 276
#define S1P 516
#define SL_W (16*S0P + 16*S1P)
#define SLICE (SL_W + 32)
#define NUG 64
#define HSLAB (256 * 2048)            // 524288
#define RSLOTS 16

// ws layout (float offsets)
#define OFF_WP    0
// packed uniform-access weight tables (inside the old OFF_WP budget):
#define OFF_PZ    0                             // [128 upg][16 k][8]
#define OFF_PH0   (OFF_PZ + 128 * 16 * 8)       // [128 upg][256 k][16] {L0 ifgo u0,u1 | ih1 ifgo u0,u1}
#define OFF_PH1   (OFF_PH0 + 128 * 256 * 16)    // [128 upg][256 k][8]  hh1
#define OFF_PB    (OFF_PH1 + 128 * 256 * 8)     // [128 upg][16]
#define OFF_WFCP  (OFF_WP + NUG * SLICE)        // [256 k][64 c] float4 {g,s,m,0}
#define OFF_H0    (OFF_WFCP + 256 * 64 * 4)     // [2][256 u][2048 m]
#define OFF_C0    (OFF_H0 + 2 * HSLAB)
#define OFF_C1    (OFF_C0 + HSLAB)
#define OFF_RING  (OFF_C1 + HSLAB)              // [16][256 u][2048 m]
#define OFF_RING2 (OFF_RING + RSLOTS * HSLAB)   // [16][2048 m][256 u]
#define WS_TOT    (OFF_RING2 + RSLOTS * HSLAB)  // ~79 MB

#define ROTL32(v, s) (((v) << (s)) | ((v) >> (32 - (s))))

// JAX threefry2x32
__host__ __device__ inline void tf2x32(uint32_t k0, uint32_t k1, uint32_t x0, uint32_t x1,
                                       uint32_t* o0, uint32_t* o1) {
  uint32_t ks2 = k0 ^ k1 ^ 0x1BD11BDAu;
  x0 += k0; x1 += k1;
  x0 += x1; x1 = ROTL32(x1, 13); x1 ^= x0;
  x0 += x1; x1 = ROTL32(x1, 15); x1 ^= x0;
  x0 += x1; x1 = ROTL32(x1, 26); x1 ^= x0;
  x0 += x1; x1 = ROTL32(x1, 6);  x1 ^= x0;
  x0 += k1; x1 += ks2 + 1u;
  x0 += x1; x1 = ROTL32(x1, 17); x1 ^= x0;
  x0 += x1; x1 = ROTL32(x1, 29); x1 ^= x0;
  x0 += x1; x1 = ROTL32(x1, 16); x1 ^= x0;
  x0 += x1; x1 = ROTL32(x1, 24); x1 ^= x0;
  x0 += ks2; x1 += k0 + 2u;
  x0 += x1; x1 = ROTL32(x1, 13); x1 ^= x0;
  x0 += x1; x1 = ROTL32(x1, 15); x1 ^= x0;
  x0 += x1; x1 = ROTL32(x1, 26); x1 ^= x0;
  x0 += x1; x1 = ROTL32(x1, 6);  x1 ^= x0;
  x0 += k0; x1 += k1 + 3u;
  x0 += x1; x1 = ROTL32(x1, 17); x1 ^= x0;
  x0 += x1; x1 = ROTL32(x1, 29); x1 ^= x0;
  x0 += x1; x1 = ROTL32(x1, 16); x1 ^= x0;
  x0 += x1; x1 = ROTL32(x1, 24); x1 ^= x0;
  x0 += k1; x1 += ks2 + 4u;
  x0 += x1; x1 = ROTL32(x1, 13); x1 ^= x0;
  x0 += x1; x1 = ROTL32(x1, 15); x1 ^= x0;
  x0 += x1; x1 = ROTL32(x1, 26); x1 ^= x0;
  x0 += x1; x1 = ROTL32(x1, 6);  x1 ^= x0;
  x0 += ks2; x1 += k0 + 5u;
  *o0 = x0; *o1 = x1;
}

__device__ inline uint32_t random_bits32(uint32_t ka, uint32_t kb, uint32_t p) {
  uint32_t a, b;
  tf2x32(ka, kb, 0u, p, &a, &b);
  return a ^ b;
}

__device__ inline float bits_to_u01(uint32_t bits) {
  return __uint_as_float((bits >> 9) | 0x3f800000u) - 1.0f;
}

__device__ inline float sigm_fast(float x) { return 1.0f / (1.0f + __expf(-x)); }

__device__ inline float erfinv_f32(float x) {
  float w = -log1pf(-x * x);
  float p;
  if (w < 5.0f) {
    w -= 2.5f;
    p = 2.81022636e-08f;
    p = fmaf(p, w, 3.43273939e-07f);
    p = fmaf(p, w, -3.5233877e-06f);
    p = fmaf(p, w, -4.39150654e-06f);
    p = fmaf(p, w, 0.00021858087f);
    p = fmaf(p, w, -0.00125372503f);
    p = fmaf(p, w, -0.00417768164f);
    p = fmaf(p, w, 0.246640727f);
    p = fmaf(p, w, 1.50140941f);
  } else {
    w = sqrtf(w) - 3.0f;
    p = -0.000200214257f;
    p = fmaf(p, w, 0.000100950558f);
    p = fmaf(p, w, 0.00134934322f);
    p = fmaf(p, w, -0.00367342844f);
    p = fmaf(p, w, 0.00573950773f);
    p = fmaf(p, w, -0.0076224613f);
    p = fmaf(p, w, 0.00943887047f);
    p = fmaf(p, w, 1.00167406f);
    p = fmaf(p, w, 2.83297682f);
  }
  return p * x;
}

__device__ inline void mdn_head(float yg, float ysg, float ym, int lane, uint32_t rid,
                                uint32_t k1a, uint32_t k1b, uint32_t k2a, uint32_t k2b,
                                float* __restrict__ out) {
  uint32_t pp = rid * (uint32_t)NCdim + (uint32_t)lane;
  uint32_t bits = random_bits32(k1a, k1b, pp);
  float u01 = bits_to_u01(bits);
  const float tinyf = 1.17549435e-38f;
  float uu = fmaxf(tinyf, u01 + tinyf);
  float gum = -logf(-logf(uu));
  float val = gum + yg;
  int idx = lane;
#pragma unroll
  for (int s = 1; s < 64; s <<= 1) {
    float ov = __shfl_xor(val, s);
    int oi = __shfl_xor(idx, s);
    if (ov > val || (ov == val && oi < idx)) { val = ov; idx = oi; }
  }
  float mu_sel = __shfl(ym, idx);
  float s_sel = __shfl(ysg, idx);

  uint32_t ebits = random_bits32(k2a, k2b, rid);
  float ue = bits_to_u01(ebits);
  const float lo = __uint_as_float(0xBF7FFFFFu);
  float un2 = fmaxf(lo, ue * 2.0f + lo);
  float eps = 1.41421356f * erfinv_f32(un2);

  float x_pred = mu_sel + expf(s_sel) * eps;

  float mx = yg;
#pragma unroll
  for (int s = 1; s < 64; s <<= 1) mx = fmaxf(mx, __shfl_xor(mx, s));
  float se = expf(yg - mx);
#pragma unroll
  for (int s = 1; s < 64; s <<= 1) se += __shfl_xor(se, s);
  float d = x_pred - ym;
  float lk = -0.5f * d * d - 66.0f * ysg - 58.812066f;
  float ts = expf(yg - mx + lk);
#pragma unroll
  for (int s = 1; s < 64; s <<= 1) ts += __shfl_xor(ts, s);
  float prob = ts / se;

  if (lane == 0) {
    out[rid] = x_pred;
    out[(size_t)Mdim * Tdim + rid] = prob;
  }
}

// Pack uniform-access weight tables + FC table.
// upg = ug*2+up; u0 = ug*4 + up*2; e(j,ty) = j*4+ty; gd = ty*256 + u0 + j.
__global__ void vfpg_prep(const float* __restrict__ Wih0, const float* __restrict__ Whh0,
                          const float* __restrict__ Wih1, const float* __restrict__ Whh1,
                          const float* __restrict__ fcW, const float* __restrict__ bih0,
                          const float* __restrict__ bhh0, const float* __restrict__ bih1,
                          const float* __restrict__ bhh1, float* __restrict__ ws) {
  int i0 = blockIdx.x * blockDim.x + threadIdx.x;
  int n = blockDim.x * gridDim.x;
  for (int i = i0; i < 128 * 16 * 8; i += n) {
    int upg = i >> 7, k = (i >> 3) & 15, e = i & 7;
    int u0 = (upg >> 1) * 4 + (upg & 1) * 2;
    int gd = (e & 3) * 256 + u0 + (e >> 2);
    ws[OFF_PZ + i] = Wih0[gd * INdim + k];
  }
  for (int i = i0; i < 128 * 256 * 16; i += n) {
    int upg = i >> 12, k = (i >> 4) & 255, e = i & 15;
    int u0 = (upg >> 1) * 4 + (upg & 1) * 2;
    int e2 = e & 7;
    int gd = (e2 & 3) * 256 + u0 + (e2 >> 2);
    ws[OFF_PH0 + i] = (e < 8) ? Whh0[gd * Hdim + k] : Wih1[gd * Hdim + k];
  }
  for (int i = i0; i < 128 * 256 * 8; i += n) {
    int upg = i >> 11, k = (i >> 3) & 255, e = i & 7;
    int u0 = (upg >> 1) * 4 + (upg & 1) * 2;
    int gd = (e & 3) * 256 + u0 + (e >> 2);
    ws[OFF_PH1 + i] = Whh1[gd * Hdim + k];
  }
  for (int i = i0; i < 128 * 16; i += n) {
    int upg = i >> 4, e = i & 15;
    int u0 = (upg >> 1) * 4 + (upg & 1) * 2;
    int e2 = e & 7;
    int gd = (e2 & 3) * 256 + u0 + (e2 >> 2);
    ws[OFF_PB + i] = (e < 8) ? (bih0[gd] + bhh0[gd]) : (bih1[gd] + bhh1[gd]);
  }
  float4* wfcp = (float4*)(ws + OFF_WFCP);
  for (int o = i0; o < 256 * 64; o += n) {
    int k = o >> 6, c = o & 63;
    wfcp[o] = make_float4(fcW[c * Hdim + k], fcW[(64 + c) * Hdim + k],
                          fcW[(128 + c) * Hdim + k], 0.0f);
  }
}

__device__ inline void fma4(float4& a, float h, float4 w) {
  a.x = fmaf(h, w.x, a.x);
  a.y = fmaf(h, w.y, a.y);
  a.z = fmaf(h, w.z, a.z);
  a.w = fmaf(h, w.w, a.w);
}

// gate-vec (i,f,g,o) -> (c,h) for one row
__device__ inline void cell1(float4 g4, float cold, float* cn, float* hn) {
  float si = sigm_fast(g4.x), sf = sigm_fast(g4.y);
  float tg = fmaf(2.0f, sigm_fast(2.0f * g4.z), -1.0f);
  float so = sigm_fast(g4.w);
  float cc = fmaf(sf, cold, si * tg);
  *cn = cc;
  *hn = so * fmaf(2.0f, sigm_fast(2.0f * cc), -1.0f);
}

// Launch t: layer0 step t (h0(t)) + layer1 step t-1 (h1(t-1)).
// MODE 0: t=0 (L0 only); 1: 1..63 (both); 2: t=64 (L1 only).
// 256 threads; wave wid: up=wid&1 (units ug*4+2up..+1), rh=wid>>1 (128-row half).
// Lane owns rows mr=mb+rh*128+2*lane (+1): 2 rows x 2 units x ifgo x 2 layers in regs.
template <int MODE>
__launch_bounds__(256, 2)
__global__ void vfpg_step(const float* __restrict__ z, const float* __restrict__ ws,
                          float* __restrict__ h0buf, float* __restrict__ c0w,
                          float* __restrict__ c1w, float* __restrict__ ring,
                          float* __restrict__ ring2, int t) {
  constexpr bool DO_L0 = (MODE <= 1);
  constexpr bool DO_L1 = (MODE >= 1);
  __shared__ __align__(16) float sbuf[2][2048];   // 16 KB: [dbuf][8 k][256 rows]

  const int tid = threadIdx.x;
  const int rg = blockIdx.x & 7;
  const int ug = blockIdx.x >> 3;
  const int mb = rg * 256;
  const int lane = tid & 63;
  const int wid = tid >> 6;
  const int up = wid & 1;
  const int rh = wid >> 1;
  const int upg = __builtin_amdgcn_readfirstlane(ug * 2 + up);
  const int rbase = rh * 128 + 2 * lane;
  const int mr = mb + rbase;
  const int kst = tid >> 6;
  const int m4 = (tid & 63) * 4;

  const float* __restrict__ PZ = ws + OFF_PZ + (size_t)upg * (16 * 8);
  const float* __restrict__ PH0 = ws + OFF_PH0 + (size_t)upg * (256 * 16);
  const float* __restrict__ PH1 = ws + OFF_PH1 + (size_t)upg * (256 * 8);
  const float* __restrict__ PB = ws + OFF_PB + (size_t)upg * 16;

  // accumulators [r][j]: float4 = (i,f,g,o)
  float4 a0[2][2], a1[2][2];
  {
    float4 b00 = *(const float4*)(PB + 0);
    float4 b01 = *(const float4*)(PB + 4);
    float4 b10 = *(const float4*)(PB + 8);
    float4 b11 = *(const float4*)(PB + 12);
    a0[0][0] = b00; a0[1][0] = b00; a0[0][1] = b01; a0[1][1] = b01;
    a1[0][0] = b10; a1[1][0] = b10; a1[0][1] = b11; a1[1][1] = b11;
  }

  // ---- Z phase: direct per-lane global loads (L0 only) ----
  if (DO_L0) {
    float zA[16], zB[16];
    {
      const float* zr0 = z + (size_t)mr * (Tdim * INdim) + t * INdim;
      const float* zr1 = zr0 + Tdim * INdim;
#pragma unroll
      for (int f4 = 0; f4 < 4; f4++) {
        *(float4*)&zA[4 * f4] = *(const float4*)(zr0 + 4 * f4);
        *(float4*)&zB[4 * f4] = *(const float4*)(zr1 + 4 * f4);
      }
    }
#pragma unroll
    for (int k = 0; k < 16; k++) {
      float4 w0 = *(const float4*)(PZ + k * 8);
      float4 w1 = *(const float4*)(PZ + k * 8 + 4);
      fma4(a0[0][0], zA[k], w0); fma4(a0[0][1], zA[k], w1);
      fma4(a0[1][0], zB[k], w0); fma4(a0[1][1], zB[k], w1);
    }
  }

  // ---- H0 phase: h0(t-1), 32 chunks of 8 k, LDS dbuf; feeds L0 and L1 ----
  if (MODE >= 1) {
    const float* h0p = h0buf + (size_t)((t - 1) & 1) * HSLAB + mb;
    float4 s0 = *(const float4*)&h0p[(size_t)kst * 2048 + m4];
    float4 s1 = *(const float4*)&h0p[(size_t)(kst + 4) * 2048 + m4];
#pragma unroll 1
    for (int kk = 0; kk < 32; kk++) {
      float* buf = sbuf[kk & 1];
      *(float4*)&buf[kst * 256 + m4] = s0;
      *(float4*)&buf[(kst + 4) * 256 + m4] = s1;
      if (kk < 31) {
        s0 = *(const float4*)&h0p[(size_t)(kk * 8 + 8 + kst) * 2048 + m4];
        s1 = *(const float4*)&h0p[(size_t)(kk * 8 + 12 + kst) * 2048 + m4];
      }
      __syncthreads();
      const float* wk = PH0 + (size_t)kk * (8 * 16);
#pragma unroll
      for (int k2 = 0; k2 < 8; k2++) {
        float2 hh = *(const float2*)&buf[k2 * 256 + rbase];
        if (DO_L0) {
          float4 wa = *(const float4*)(wk + k2 * 16);
          float4 wb = *(const float4*)(wk + k2 * 16 + 4);
          fma4(a0[0][0], hh.x, wa); fma4(a0[0][1], hh.x, wb);
          fma4(a0[1][0], hh.y, wa); fma4(a0[1][1], hh.y, wb);
        }
        if (DO_L1) {
          float4 wc = *(const float4*)(wk + k2 * 16 + 8);
          float4 wd = *(const float4*)(wk + k2 * 16 + 12);
          fma4(a1[0][0], hh.x, wc); fma4(a1[0][1], hh.x, wd);
          fma4(a1[1][0], hh.y, wc); fma4(a1[1][1], hh.y, wd);
        }
      }
    }
  }

  // ---- L0 cell update (lane-local) ----
  if (DO_L0) {
    float* h0c = h0buf + (size_t)(t & 1) * HSLAB;
#pragma unroll
    for (int j = 0; j < 2; j++) {
      int u = ug * 4 + up * 2 + j;
      size_t idx = (size_t)u * 2048 + mr;
      float2 cold = make_float2(0.0f, 0.0f);
      if (MODE == 1) cold = *(const float2*)&c0w[idx];
      float2 cn, hn;
      cell1(a0[0][j], cold.x, &cn.x, &hn.x);
      cell1(a0[1][j], cold.y, &cn.y, &hn.y);
      *(float2*)&c0w[idx] = cn;
      *(float2*)&h0c[idx] = hn;
    }
  }

  // ---- H1 phase: h1(t-2), 32 chunks; feeds L1 ----
  if (DO_L1 && t >= 2) {
    const float* h1p = ring + (size_t)((t - 2) & 15) * HSLAB + mb;
    float4 s0 = *(const float4*)&h1p[(size_t)kst * 2048 + m4];
    float4 s1 = *(const float4*)&h1p[(size_t)(kst + 4) * 2048 + m4];
    __syncthreads();   // drain H0 reads before overwriting sbuf[0]
#pragma unroll 1
    for (int kk = 0; kk < 32; kk++) {
      float* buf = sbuf[kk & 1];
      *(float4*)&buf[kst * 256 + m4] = s0;
      *(float4*)&buf[(kst + 4) * 256 + m4] = s1;
      if (kk < 31) {
        s0 = *(const float4*)&h1p[(size_t)(kk * 8 + 8 + kst) * 2048 + m4];
        s1 = *(const float4*)&h1p[(size_t)(kk * 8 + 12 + kst) * 2048 + m4];
      }
      __syncthreads();
      const float* wk = PH1 + (size_t)kk * (8 * 8);
#pragma unroll
      for (int k2 = 0; k2 < 8; k2++) {
        float2 hh = *(const float2*)&buf[k2 * 256 + rbase];
        float4 wc = *(const float4*)(wk + k2 * 8);
        float4 wd = *(const float4*)(wk + k2 * 8 + 4);
        fma4(a1[0][0], hh.x, wc); fma4(a1[0][1], hh.x, wd);
        fma4(a1[1][0], hh.y, wc); fma4(a1[1][1], hh.y, wd);
      }
    }
  }

  // ---- L1 cell update (h1(t-1)) ----
  if (DO_L1) {
    int slot = (t - 1) & 15;
    float* r1 = ring + (size_t)slot * HSLAB;
    float* r2 = ring2 + (size_t)slot * HSLAB;
    float2 hns[2];
#pragma unroll
    for (int j = 0; j < 2; j++) {
      int u = ug * 4 + up * 2 + j;
      size_t idx = (size_t)u * 2048 + mr;
      float2 cold = make_float2(0.0f, 0.0f);
      if (t >= 2) cold = *(const float2*)&c1w[idx];
      float2 cn, hn;
      cell1(a1[0][j], cold.x, &cn.x, &hn.x);
      cell1(a1[1][j], cold.y, &cn.y, &hn.y);
      *(float2*)&c1w[idx] = cn;
      *(float2*)&r1[idx] = hn;
      hns[j] = hn;
    }
    int u0 = ug * 4 + up * 2;
    *(float2*)&r2[(size_t)mr * 256 + u0] = make_float2(hns[0].x, hns[1].x);
    *(float2*)&r2[(size_t)(mr + 1) * 256 + u0] = make_float2(hns[0].y, hns[1].y);
  }
}

// Head: FC + MDN for 16 slots x 2048 rows; wave = 8 rows (w-loads shared).
__launch_bounds__(512, 2)
__global__ void vfpg_head(const float* __restrict__ ws, const float* __restrict__ fcb,
                          float* __restrict__ out, int tbase,
                          uint32_t k1a, uint32_t k1b, uint32_t k2a, uint32_t k2b) {
  __shared__ __align__(16) float hsw[8][8][Hdim];   // 64 KB
  const int tid = threadIdx.x;
  const int lane = tid & 63, wid = tid >> 6;
  const int rb8 = blockIdx.x * 8 + wid;
  const int slot = rb8 >> 8;
  const int mbase = (rb8 & 255) * 8;

  const float* r2 = ws + OFF_RING2 + (size_t)slot * HSLAB + (size_t)mbase * 256;
  const float4* WFCP = (const float4*)(ws + OFF_WFCP);

#pragma unroll
  for (int rr = 0; rr < 8; rr++)
    *(float4*)&hsw[wid][rr][lane * 4] = *(const float4*)&r2[rr * 256 + lane * 4];
  __builtin_amdgcn_s_waitcnt(0);

  float yg[8], ys[8], ym[8];
#pragma unroll
  for (int rr = 0; rr < 8; rr++) {
    yg[rr] = fcb[lane]; ys[rr] = fcb[64 + lane]; ym[rr] = fcb[128 + lane];
  }
#pragma unroll 2
  for (int k4 = 0; k4 < 64; k4++) {
#pragma unroll
    for (int j = 0; j < 4; j++) {
      float4 w = WFCP[(k4 * 4 + j) * 64 + lane];
#pragma unroll
      for (int rr = 0; rr < 8; rr++) {
        float hv = hsw[wid][rr][k4 * 4 + j];
        yg[rr] = fmaf(hv, w.x, yg[rr]);
        ys[rr] = fmaf(hv, w.y, ys[rr]);
        ym[rr] = fmaf(hv, w.z, ym[rr]);
      }
    }
  }
  int tt = tbase + slot;
#pragma unroll 1
  for (int rr = 0; rr < 8; rr++) {
    uint32_t rid = (uint32_t)(mbase + rr) * Tdim + (uint32_t)tt;
    mdn_head(yg[rr], ys[rr], ym[rr], lane, rid, k1a, k1b, k2a, k2b, out);
  }
}

extern "C" void kernel_launch(void* const* d_in, const int* in_sizes, int n_in,
                              void* d_out, int out_size, void* d_ws, size_t ws_size,
                              hipStream_t stream) {
  const float* z    = (const float*)d_in[0];
  const float* Wih0 = (const float*)d_in[1];
  const float* Whh0 = (const float*)d_in[2];
  const float* bih0 = (const float*)d_in[3];
  const float* bhh0 = (const float*)d_in[4];
  const float* Wih1 = (const float*)d_in[5];
  const float* Whh1 = (const float*)d_in[6];
  const float* bih1 = (const float*)d_in[7];
  const float* bhh1 = (const float*)d_in[8];
  const float* fcW  = (const float*)d_in[9];
  const float* fcb  = (const float*)d_in[10];
  float* ws = (float*)d_ws;
  float* out = (float*)d_out;

  if (ws_size < (size_t)WS_TOT * sizeof(float)) return;

  vfpg_prep<<<dim3(512), dim3(256), 0, stream>>>(
      Wih0, Whh0, Wih1, Whh1, fcW, bih0, bhh0, bih1, bhh1, ws);

  uint32_t k1a, k1b, k2a, k2b;
  tf2x32(0u, 42u, 0u, 0u, &k1a, &k1b);
  tf2x32(0u, 42u, 0u, 1u, &k2a, &k2b);

  float* h0buf = ws + OFF_H0;
  float* c0w = ws + OFF_C0;
  float* c1w = ws + OFF_C1;
  float* ring = ws + OFF_RING;
  float* ring2 = ws + OFF_RING2;

  vfpg_step<0><<<dim3(512), dim3(256), 0, stream>>>(z, ws, h0buf, c0w, c1w, ring, ring2, 0);
  for (int t = 1; t <= 63; t++) {
    vfpg_step<1><<<dim3(512), dim3(256), 0, stream>>>(z, ws, h0buf, c0w, c1w, ring, ring2, t);
    if (t == 16 || t == 32 || t == 48) {
      vfpg_head<<<dim3(512), dim3(512), 0, stream>>>(ws, fcb, out, t - 16,
                                                     k1a, k1b, k2a, k2b);
    }
  }
  vfpg_step<2><<<dim3(512), dim3(256), 0, stream>>>(z, ws, h0buf, c0w, c1w, ring, ring2, 64);
  vfpg_head<<<dim3(512), dim3(512), 0, stream>>>(ws, fcb, out, 48, k1a, k1b, k2a, k2b);
}